// Round 5
// baseline (13659.862 us; speedup 1.0000x reference)
//
#include <hip/hip_runtime.h>
#include <stdint.h>

#define B_ 4
#define N_ 5000
#define T_ 12
#define FH_ 12
#define H_ 128
#define BN_ 20000
#define E_ 320000
#define TOTE_ (E_ + BN_)
#define NTILE_B 313   // 16-row tiles per batch (last has 8 rows)
#define PGRID 1256    // 8 groups x 157 blocks
#define GSZ 157

typedef __attribute__((ext_vector_type(8))) short s8v;
typedef __attribute__((ext_vector_type(4))) float f32x4;

__device__ __forceinline__ float fast_tanh(float x) {
  float e = __expf(2.f * x);
  return 1.f - 2.f * __builtin_amdgcn_rcpf(e + 1.f);
}
__device__ __forceinline__ float fast_sigmoid(float x) {
  return __builtin_amdgcn_rcpf(1.f + __expf(-x));
}
__device__ __forceinline__ unsigned short f2bf(float f) {  // RNE
  unsigned u = __float_as_uint(f);
  u = (u + 0x7fffu + ((u >> 16) & 1u)) >> 16;
  return (unsigned short)u;
}
__device__ __forceinline__ float bf2f(unsigned short u) {
  return __uint_as_float(((unsigned)u) << 16);
}

__global__ void k_sentinel(float* out) { out[0] = 1e30f; }
__global__ void k_zero(int* p, int n) {
  int i = blockIdx.x * 256 + threadIdx.x;
  if (i < n) p[i] = 0;
}

__global__ void k_init_cnt(int* cnt) {
  int i = blockIdx.x * 256 + threadIdx.x;
  if (i < BN_) cnt[i] = 1;  // self-loop
}
__global__ void k_count(const int* __restrict__ dst, int* cnt) {
  int e = blockIdx.x * 256 + threadIdx.x;
  if (e < E_) atomicAdd(&cnt[dst[e]], 1);
}
__global__ void k_dinv(const int* __restrict__ cnt, float* __restrict__ dinv) {
  int i = blockIdx.x * 256 + threadIdx.x;
  if (i < BN_) dinv[i] = rsqrtf((float)cnt[i]);
}
__global__ void k_scan(int* cnt, int* rp) {
  __shared__ int sh[1024];
  int tid = threadIdx.x;
  const int per = (BN_ + 1023) / 1024;
  int start = tid * per;
  int end = start + per; if (end > BN_) end = BN_;
  int s = 0;
  for (int i = start; i < end; i++) s += cnt[i];
  sh[tid] = s;
  __syncthreads();
  for (int off = 1; off < 1024; off <<= 1) {
    int v = (tid >= off) ? sh[tid - off] : 0;
    __syncthreads();
    sh[tid] += v;
    __syncthreads();
  }
  int run = (tid > 0) ? sh[tid - 1] : 0;
  for (int i = start; i < end; i++) {
    int c = cnt[i];
    rp[i] = run;
    run += c;
    cnt[i] = 0;
  }
  if (tid == 1023) rp[BN_] = sh[1023];
}
__global__ void k_fill(const int* __restrict__ src, const int* __restrict__ dst,
                       const int* __restrict__ rp, int* cnt, int2* ev,
                       const float* __restrict__ dinv) {
  int e = blockIdx.x * 256 + threadIdx.x;
  if (e >= TOTE_) return;
  int s, d;
  if (e < E_) { s = src[e]; d = dst[e]; }
  else { s = d = e - E_; }
  int pos = rp[d] + atomicAdd(&cnt[d], 1);
  int2 p; p.x = s; p.y = __float_as_int(dinv[s] * dinv[d]);
  ev[pos] = p;
}

// pack weight into MFMA B-frag layout
__global__ void k_prep(const float* __restrict__ src, unsigned short* __restrict__ dst,
                       int K, int Nn, int transposed) {
  int idx = blockIdx.x * 256 + threadIdx.x;
  if (idx >= K * Nn) return;
  int j = idx & 7, l = (idx >> 3) & 63, rest = idx >> 9;
  int NT = Nn >> 4;
  int nt = rest % NT, kc = rest / NT;
  int k = kc * 32 + ((l >> 4) << 3) + j;
  int n = nt * 16 + (l & 15);
  float v = transposed ? src[n * K + k] : src[k * Nn + n];
  dst[idx] = f2bf(v);
}

// all-T layer1: per row, 12 aggregates + relu(agg*w1+b1) -> h1[t][row][64]
__global__ void k_spl1T(const int* __restrict__ rp, const int2* __restrict__ ev,
                        const float* __restrict__ x,
                        const float* __restrict__ w1, const float* __restrict__ b1,
                        unsigned short* __restrict__ h1) {
  int wid = (blockIdx.x * 256 + threadIdx.x) >> 6;
  int lane = threadIdx.x & 63;
  if (wid >= BN_) return;
  int beg = rp[wid], end = rp[wid + 1];
  float a[12];
#pragma unroll
  for (int t = 0; t < 12; t++) a[t] = 0.f;
  for (int e = beg + lane; e < end; e += 64) {
    int2 p = ev[e];
    const float4* xp = (const float4*)(x + (size_t)p.x * 12);
    float v = __int_as_float(p.y);
    float4 x0 = xp[0], x1 = xp[1], x2 = xp[2];
    a[0] = fmaf(v, x0.x, a[0]);  a[1] = fmaf(v, x0.y, a[1]);
    a[2] = fmaf(v, x0.z, a[2]);  a[3] = fmaf(v, x0.w, a[3]);
    a[4] = fmaf(v, x1.x, a[4]);  a[5] = fmaf(v, x1.y, a[5]);
    a[6] = fmaf(v, x1.z, a[6]);  a[7] = fmaf(v, x1.w, a[7]);
    a[8] = fmaf(v, x2.x, a[8]);  a[9] = fmaf(v, x2.y, a[9]);
    a[10] = fmaf(v, x2.z, a[10]); a[11] = fmaf(v, x2.w, a[11]);
  }
#pragma unroll
  for (int t = 0; t < 12; t++)
#pragma unroll
    for (int m = 1; m < 64; m <<= 1) a[t] += __shfl_xor(a[t], m);
  float wv = w1[lane], bv = b1[lane];
#pragma unroll
  for (int t = 0; t < 12; t++) {
    float v = fmaf(a[t], wv, bv);
    h1[((size_t)t * BN_ + wid) * 64 + lane] = f2bf(fmaxf(v, 0.f));
  }
}

// interleaved 4-row gather for wave w into padded LDS tile
template<int KIN>
__device__ __forceinline__ void gather_tile(
    const int* __restrict__ rp, const int2* __restrict__ ev,
    const unsigned short* in, unsigned short (*agg)[KIN + 8],
    int w, int l, int row0g, int nvalid) {
  int begs[4], lens[4], mx = 0;
  float a0[4], a1[4];
#pragma unroll
  for (int r = 0; r < 4; r++) {
    int lr = w * 4 + r;
    bool ok = lr < nvalid;
    int b0 = ok ? rp[row0g + lr] : 0;
    int e0 = ok ? rp[row0g + lr + 1] : 0;
    begs[r] = b0; lens[r] = e0 - b0;
    mx = lens[r] > mx ? lens[r] : mx;
    a0[r] = 0.f; a1[r] = 0.f;
  }
  for (int i = 0; i < mx; i++) {
#pragma unroll
    for (int r = 0; r < 4; r++) {
      if (i < lens[r]) {
        int2 e = ev[begs[r] + i];
        float v = __int_as_float(e.y);
        if (KIN == 128) {
          unsigned p = *(const unsigned*)(in + (size_t)e.x * 128 + l * 2);
          a0[r] = fmaf(v, bf2f((unsigned short)(p & 0xffffu)), a0[r]);
          a1[r] = fmaf(v, bf2f((unsigned short)(p >> 16)), a1[r]);
        } else {
          a0[r] = fmaf(v, bf2f(in[(size_t)e.x * 64 + l]), a0[r]);
        }
      }
    }
  }
#pragma unroll
  for (int r = 0; r < 4; r++) {
    if (KIN == 128)
      *(unsigned*)&agg[w * 4 + r][l * 2] = ((unsigned)f2bf(a1[r]) << 16) | f2bf(a0[r]);
    else
      agg[w * 4 + r][l] = f2bf(a0[r]);
  }
}

template<int KIN>
__device__ __forceinline__ void mfma_tile(
    const unsigned short (*agg)[KIN + 8], const unsigned short* __restrict__ Wf,
    int w, int l, f32x4 acc[2]) {
  constexpr int KC = KIN / 32;
  const int hi = l >> 4, lo16 = l & 15;
  acc[0] = (f32x4){0.f, 0.f, 0.f, 0.f};
  acc[1] = (f32x4){0.f, 0.f, 0.f, 0.f};
#pragma unroll
  for (int kc = 0; kc < KC; kc++) {
    s8v av = *(const s8v*)&agg[lo16][kc * 32 + hi * 8];
#pragma unroll
    for (int q = 0; q < 2; q++) {
      s8v bv = *(const s8v*)(Wf + (((size_t)(kc * 8 + 2 * w + q)) << 9) + (l << 3));
      acc[q] = __builtin_amdgcn_mfma_f32_16x16x32_bf16(av, bv, acc[q], 0, 0, 0);
    }
  }
}

// spatial fused SpMM+GEMM (relu), batched over t = blockIdx.y
template<int KIN>
__global__ __launch_bounds__(256) void k_fusedT(
    const int* __restrict__ rp, const int2* __restrict__ ev,
    const unsigned short* __restrict__ inb, const unsigned short* __restrict__ Wf,
    const float* __restrict__ bias, unsigned short* __restrict__ outb) {
  __shared__ unsigned short agg[16][KIN + 8];
  const int tid = threadIdx.x, l = tid & 63, w = tid >> 6;
  const int t = blockIdx.y;
  const unsigned short* in = inb + (size_t)t * BN_ * KIN;
  unsigned short* out = outb + (size_t)t * BN_ * 128;
  const int bid = blockIdx.x;
  const int xcd = bid & 7, slot = bid >> 3;
  const int bb = xcd >> 1;
  const int within = slot * 2 + (xcd & 1);
  const int wr0 = within * 16;
  int nv = N_ - wr0; nv = nv > 16 ? 16 : nv;
  if (nv <= 0) return;
  const int row0g = bb * N_ + wr0;
  gather_tile<KIN>(rp, ev, in, agg, w, l, row0g, nv);
  __syncthreads();
  f32x4 acc[2];
  mfma_tile<KIN>(agg, Wf, w, l, acc);
  const int hi = l >> 4, lo16 = l & 15;
#pragma unroll
  for (int q = 0; q < 2; q++) {
    int col = (2 * w + q) * 16 + lo16;
    float bi = bias[col];
#pragma unroll
    for (int reg = 0; reg < 4; reg++) {
      int lr = hi * 4 + reg;
      if (lr < nv)
        out[(size_t)(row0g + lr) * 128 + col] = f2bf(fmaxf(acc[q][reg] + bi, 0.f));
    }
  }
}

// two-level device barrier (groups of GSZ blocks, 8 groups)
__device__ __forceinline__ void gbar(int* xctr, int* gctr, int* gflag, int grp, int ph) {
  __syncthreads();
  if (threadIdx.x == 0) {
    __threadfence();
    int prev = __hip_atomic_fetch_add(&xctr[grp * 16], 1, __ATOMIC_ACQ_REL,
                                      __HIP_MEMORY_SCOPE_AGENT);
    if (prev == GSZ * ph - 1) {
      int gp = __hip_atomic_fetch_add(gctr, 1, __ATOMIC_ACQ_REL,
                                      __HIP_MEMORY_SCOPE_AGENT);
      if (gp == 8 * ph - 1)
        __hip_atomic_store(gflag, ph, __ATOMIC_RELEASE, __HIP_MEMORY_SCOPE_AGENT);
    }
    while (__hip_atomic_load(gflag, __ATOMIC_RELAXED, __HIP_MEMORY_SCOPE_AGENT) < ph)
      __builtin_amdgcn_s_sleep(2);
    (void)__hip_atomic_load(gflag, __ATOMIC_ACQUIRE, __HIP_MEMORY_SCOPE_AGENT);
    __threadfence();
  }
  __syncthreads();
}

// persistent RK4 ODE: 11 steps x 4 stages x 2 GCN layers, 87 device barriers.
// grid MUST be PGRID blocks of 256 thr; launch_bounds(256,6) => >=6 blk/CU capacity.
__global__ __launch_bounds__(256, 6) void k_ode(
    const int* __restrict__ rp, const int2* __restrict__ ev,
    const unsigned short* __restrict__ ow1f, const unsigned short* __restrict__ ow2f,
    const float* __restrict__ ob1, const float* __restrict__ ob2,
    unsigned short* hbf, unsigned short* ubf, unsigned short* t1, unsigned short* rkb,
    float* hst,
    const float* __restrict__ ow, const float* __restrict__ ob,
    float* outp, int* xctr, int* gctr, int* gflag) {
  __shared__ unsigned short agg[16][136];
  __shared__ float ppart[4][16];
  const int tid = threadIdx.x, l = tid & 63, w = tid >> 6;
  const int bid = blockIdx.x;
  const int grp = bid & 7, j = bid >> 3;
  const int bb = grp >> 1;
  const int tb = (grp & 1) + 2 * j;        // within-batch 16-row tile
  const bool tvalid = tb < NTILE_B;
  const int wr0 = tb * 16;
  int nv = tvalid ? (N_ - wr0 > 16 ? 16 : N_ - wr0) : 0;
  const int row0g = bb * N_ + wr0;
  const int hi = l >> 4, lo16 = l & 15;
  const float dt = (float)FH_ / (float)(FH_ - 1);
  int ph = 0;

  for (int s = 1; s < FH_; s++) {
    for (int st = 0; st < 4; st++) {
      // ---- layer 1: t1 = tanh(S*src @ W1 + b1) ----
      if (tvalid) {
        const unsigned short* src = (st == 0) ? hbf : ubf;
        gather_tile<128>(rp, ev, src, agg, w, l, row0g, nv);
        __syncthreads();
        f32x4 acc[2];
        mfma_tile<128>(agg, ow1f, w, l, acc);
#pragma unroll
        for (int q = 0; q < 2; q++) {
          int col = (2 * w + q) * 16 + lo16;
          float bi = ob1[col];
#pragma unroll
          for (int reg = 0; reg < 4; reg++) {
            int lr = hi * 4 + reg;
            if (lr < nv)
              t1[(size_t)(row0g + lr) * 128 + col] = f2bf(fast_tanh(acc[q][reg] + bi));
          }
        }
      }
      ph++; gbar(xctr, gctr, gflag, grp, ph);
      // ---- layer 2: k = tanh(S*t1 @ W2 + b2), fused RK4 epilogue ----
      if (tvalid) {
        gather_tile<128>(rp, ev, t1, agg, w, l, row0g, nv);
        __syncthreads();
        f32x4 acc[2];
        mfma_tile<128>(agg, ow2f, w, l, acc);
        float c1 = (st <= 1) ? 0.5f * dt : dt;
        float p[4] = {0.f, 0.f, 0.f, 0.f};
#pragma unroll
        for (int q = 0; q < 2; q++) {
          int col = (2 * w + q) * 16 + lo16;
          float bi = ob2[col];
          float owv = ow[col];
#pragma unroll
          for (int reg = 0; reg < 4; reg++) {
            int lr = hi * 4 + reg;
            if (lr >= nv) continue;
            size_t oi = (size_t)(row0g + lr) * 128 + col;
            float v = fast_tanh(acc[q][reg] + bi);
            if (st == 0) {
              rkb[oi] = f2bf(v);
              ubf[oi] = f2bf(fmaf(c1, v, bf2f(hbf[oi])));
            } else if (st < 3) {
              rkb[oi] = f2bf(bf2f(rkb[oi]) + 2.f * v);
              ubf[oi] = f2bf(fmaf(c1, v, bf2f(hbf[oi])));
            } else {
              float nh = fmaf(dt / 6.f, bf2f(rkb[oi]) + v, hst[oi]);
              hst[oi] = nh;
              hbf[oi] = f2bf(nh);
              p[reg] = fmaf(nh, owv, p[reg]);
            }
          }
        }
        if (st == 3) {
#pragma unroll
          for (int m = 1; m <= 8; m <<= 1)
#pragma unroll
            for (int reg = 0; reg < 4; reg++) p[reg] += __shfl_xor(p[reg], m);
          if (lo16 == 0)
#pragma unroll
            for (int reg = 0; reg < 4; reg++) ppart[w][hi * 4 + reg] = p[reg];
          __syncthreads();
          if (tid < 16 && tid < nv)
            outp[(size_t)(row0g + tid) * FH_ + s] =
                ppart[0][tid] + ppart[1][tid] + ppart[2][tid] + ppart[3][tid] + ob[0];
        }
      }
      if (!(s == FH_ - 1 && st == 3)) { ph++; gbar(xctr, gctr, gflag, grp, ph); }
    }
  }
}

// plain MFMA GEMM (attention scores mode 4, GRU mode 0 -> fp32 out)
template<int KC>
__global__ __launch_bounds__(256) void k_mgemm(
    const unsigned short* __restrict__ A, const unsigned short* __restrict__ Wf,
    const float* __restrict__ bias, int nrows, int NTt, int mode,
    float* __restrict__ outf, int ldout,
    const float* __restrict__ w2v, const float* __restrict__ b2,
    float* __restrict__ scores) {
  const int tid = threadIdx.x;
  const int l = tid & 63;
  const int w = tid >> 6;
  const int m0 = blockIdx.x * 64 + w * 16;
  const int cb = blockIdx.y * 128;
  const int ntg0 = blockIdx.y * 8;
  const int K = KC * 32;

  f32x4 acc[8];
#pragma unroll
  for (int nt = 0; nt < 8; nt++) acc[nt] = (f32x4){0.f, 0.f, 0.f, 0.f};

  int arow = m0 + (l & 15);
  if (arow >= nrows) arow = nrows - 1;
  const unsigned short* Ap = A + (size_t)arow * K + ((l >> 4) << 3);

#pragma unroll
  for (int kc = 0; kc < KC; kc++) {
    s8v av = *(const s8v*)(Ap + kc * 32);
#pragma unroll
    for (int nt = 0; nt < 8; nt++) {
      const unsigned short* bp = Wf + (((size_t)((kc * NTt) + ntg0 + nt)) << 9) + (l << 3);
      s8v bv = *(const s8v*)bp;
      acc[nt] = __builtin_amdgcn_mfma_f32_16x16x32_bf16(av, bv, acc[nt], 0, 0, 0);
    }
  }

  if (mode == 4) {
    float p[4] = {0.f, 0.f, 0.f, 0.f};
#pragma unroll
    for (int nt = 0; nt < 8; nt++) {
      int col = nt * 16 + (l & 15);
      float bi = bias[col], wv = w2v[col];
#pragma unroll
      for (int reg = 0; reg < 4; reg++)
        p[reg] = fmaf(fast_tanh(acc[nt][reg] + bi), wv, p[reg]);
    }
#pragma unroll
    for (int m = 1; m <= 8; m <<= 1)
#pragma unroll
      for (int reg = 0; reg < 4; reg++) p[reg] += __shfl_xor(p[reg], m);
    if ((l & 15) == 0) {
      float bb = b2[0];
#pragma unroll
      for (int reg = 0; reg < 4; reg++) {
        int row = m0 + ((l >> 4) << 2) + reg;
        if (row < nrows) scores[row] = p[reg] + bb;
      }
    }
    return;
  }

#pragma unroll
  for (int nt = 0; nt < 8; nt++) {
    int col = cb + nt * 16 + (l & 15);
    float bi = bias[col];
#pragma unroll
    for (int reg = 0; reg < 4; reg++) {
      int row = m0 + ((l >> 4) << 2) + reg;
      if (row >= nrows) continue;
      outf[(size_t)row * ldout + col] = acc[nt][reg] + bi;
    }
  }
}

__global__ void k_softmax(const float* __restrict__ sc, float* __restrict__ aw) {
  int bn = blockIdx.x * 256 + threadIdx.x;
  if (bn >= BN_) return;
  float v[T_];
  float m = -1e30f;
#pragma unroll
  for (int t = 0; t < T_; t++) { v[t] = sc[t * BN_ + bn]; m = fmaxf(m, v[t]); }
  float s = 0.f;
#pragma unroll
  for (int t = 0; t < T_; t++) { v[t] = __expf(v[t] - m); s += v[t]; }
  float inv = __builtin_amdgcn_rcpf(s);
#pragma unroll
  for (int t = 0; t < T_; t++) aw[t * BN_ + bn] = v[t] * inv;
}

__global__ void k_wsum(const float* __restrict__ aw, const unsigned short* __restrict__ hs,
                       unsigned short* __restrict__ nf) {
  int idx = blockIdx.x * 256 + threadIdx.x;
  if (idx >= BN_ * H_) return;
  int bn = idx >> 7, f = idx & 127;
  float s = 0.f;
#pragma unroll
  for (int t = 0; t < T_; t++)
    s = fmaf(aw[t * BN_ + bn], bf2f(hs[((size_t)t * BN_ + bn) * H_ + f]), s);
  nf[idx] = f2bf(s);
}

__global__ void k_gru(const float* __restrict__ gi, const float* __restrict__ bhh,
                      float* __restrict__ h, unsigned short* __restrict__ hbf) {
  int idx = blockIdx.x * 256 + threadIdx.x;
  if (idx >= BN_ * H_) return;
  int bn = idx >> 7, jj = idx & 127;
  const float* g = gi + (size_t)bn * 384;
  float r = fast_sigmoid(g[jj] + bhh[jj]);
  float z = fast_sigmoid(g[128 + jj] + bhh[128 + jj]);
  float n = fast_tanh(g[256 + jj] + r * bhh[256 + jj]);
  float hv = (1.f - z) * n;  // h0 = 0
  h[idx] = hv;
  hbf[idx] = f2bf(hv);
}

__global__ void k_proj(const float* __restrict__ st, const float* __restrict__ ow,
                       const float* __restrict__ ob, float* __restrict__ out, int fh) {
  int wid = (blockIdx.x * blockDim.x + threadIdx.x) >> 6;
  int lane = threadIdx.x & 63;
  if (wid >= BN_) return;
  float2 a = ((const float2*)(st + (size_t)wid * 128))[lane];
  float2 w = ((const float2*)ow)[lane];
  float s = a.x * w.x + a.y * w.y;
#pragma unroll
  for (int off = 32; off > 0; off >>= 1) s += __shfl_down(s, off);
  if (lane == 0) out[(size_t)wid * FH_ + fh] = s + ob[0];
}

extern "C" void kernel_launch(void* const* d_in, const int* in_sizes, int n_in,
                              void* d_out, int out_size, void* d_ws, size_t ws_size,
                              hipStream_t stream) {
  const float* x       = (const float*)d_in[0];
  const float* gcn_w1  = (const float*)d_in[1];
  const float* gcn_b1  = (const float*)d_in[2];
  const float* gcn_w2  = (const float*)d_in[3];
  const float* gcn_b2  = (const float*)d_in[4];
  const float* gcn_w3  = (const float*)d_in[5];
  const float* gcn_b3  = (const float*)d_in[6];
  const float* att_w1  = (const float*)d_in[7];
  const float* att_b1  = (const float*)d_in[8];
  const float* att_w2  = (const float*)d_in[9];
  const float* att_b2  = (const float*)d_in[10];
  const float* gru_wih = (const float*)d_in[11];
  const float* gru_bih = (const float*)d_in[13];
  const float* gru_bhh = (const float*)d_in[14];
  const float* ode_w1  = (const float*)d_in[15];
  const float* ode_b1  = (const float*)d_in[16];
  const float* ode_w2  = (const float*)d_in[17];
  const float* ode_b2  = (const float*)d_in[18];
  const float* out_w   = (const float*)d_in[19];
  const float* out_b   = (const float*)d_in[20];
  const int*   eidx    = (const int*)d_in[21];
  float* out = (float*)d_out;

  float* wsf = (float*)d_ws;
  size_t off = 0;
  float* gi = wsf + off;                                  // BN*384 f32
  unsigned short* h1bf12 = (unsigned short*)gi;           // alias: 12*BN*64 bf16 (same bytes)
  off += (size_t)BN_ * 384;
  float* hst    = wsf + off; off += (size_t)BN_ * H_;
  float* scores = wsf + off; off += (size_t)T_ * BN_;
  float* aw     = wsf + off; off += (size_t)T_ * BN_;
  float* dinv   = wsf + off; off += BN_;
  int2*  ev     = (int2*)(wsf + off); off += (size_t)TOTE_ * 2;
  unsigned short* hseqb  = (unsigned short*)(wsf + off); off += (size_t)T_ * BN_ * H_ / 2;
  unsigned short* t1bf12 = (unsigned short*)(wsf + off); off += (size_t)T_ * BN_ * H_ / 2;
  unsigned short* hbf    = (unsigned short*)(wsf + off); off += (size_t)BN_ * H_ / 2;
  unsigned short* ubf    = (unsigned short*)(wsf + off); off += (size_t)BN_ * H_ / 2;
  unsigned short* rkb    = (unsigned short*)(wsf + off); off += (size_t)BN_ * H_ / 2;
  unsigned short* nfbf   = (unsigned short*)(wsf + off); off += (size_t)BN_ * H_ / 2;
  unsigned short* w2f    = (unsigned short*)(wsf + off); off += 64 * 128 / 2;
  unsigned short* w3f    = (unsigned short*)(wsf + off); off += 128 * 128 / 2;
  unsigned short* aw1f   = (unsigned short*)(wsf + off); off += 128 * 128 / 2;
  unsigned short* ow1f   = (unsigned short*)(wsf + off); off += 128 * 128 / 2;
  unsigned short* ow2f   = (unsigned short*)(wsf + off); off += 128 * 128 / 2;
  unsigned short* wihf   = (unsigned short*)(wsf + off); off += 128 * 384 / 2;
  int* rp  = (int*)(wsf + off); off += BN_ + 1;
  int* cnt = (int*)(wsf + off); off += BN_;
  int* bar = (int*)(wsf + off); off += 256;               // xctr[128], gctr, gflag
  if (ws_size < off * sizeof(float)) {
    k_sentinel<<<1, 1, 0, stream>>>(out);
    return;
  }
  int* xctr = bar;
  int* gctr = bar + 128;
  int* gflag = bar + 129;

  const int* esrc = eidx;
  const int* edst = eidx + E_;

  // ---- CSR build + weight prep ----
  k_init_cnt<<<(BN_ + 255) / 256, 256, 0, stream>>>(cnt);
  k_count<<<(E_ + 255) / 256, 256, 0, stream>>>(edst, cnt);
  k_dinv<<<(BN_ + 255) / 256, 256, 0, stream>>>(cnt, dinv);
  k_scan<<<1, 1024, 0, stream>>>(cnt, rp);
  k_fill<<<(TOTE_ + 255) / 256, 256, 0, stream>>>(esrc, edst, rp, cnt, ev, dinv);
  k_zero<<<1, 256, 0, stream>>>(bar, 256);
  k_prep<<<(64 * 128 + 255) / 256, 256, 0, stream>>>(gcn_w2, w2f, 64, 128, 0);
  k_prep<<<(128 * 128 + 255) / 256, 256, 0, stream>>>(gcn_w3, w3f, 128, 128, 0);
  k_prep<<<(128 * 128 + 255) / 256, 256, 0, stream>>>(att_w1, aw1f, 128, 128, 0);
  k_prep<<<(128 * 128 + 255) / 256, 256, 0, stream>>>(ode_w1, ow1f, 128, 128, 0);
  k_prep<<<(128 * 128 + 255) / 256, 256, 0, stream>>>(ode_w2, ow2f, 128, 128, 0);
  k_prep<<<(128 * 384 + 255) / 256, 256, 0, stream>>>(gru_wih, wihf, 128, 384, 1);

  const int gW = BN_ / 4;
  const int gR = (BN_ + 63) / 64;
  const int gE = (BN_ * H_ + 255) / 256;

  // ---- spatial encoder: 3 dispatches for all 12 timesteps ----
  k_spl1T<<<gW, 256, 0, stream>>>(rp, ev, x, gcn_w1, gcn_b1, h1bf12);
  k_fusedT<64><<<dim3(1280, 12), 256, 0, stream>>>(rp, ev, h1bf12, w2f, gcn_b2, t1bf12);
  k_fusedT<128><<<dim3(1280, 12), 256, 0, stream>>>(rp, ev, t1bf12, w3f, gcn_b3, hseqb);

  // ---- temporal attention ----
  k_mgemm<4><<<dim3((T_ * BN_ + 63) / 64, 1), 256, 0, stream>>>(
      hseqb, aw1f, att_b1, T_ * BN_, 8, 4, nullptr, 128, att_w2, att_b2, scores);
  k_softmax<<<(BN_ + 255) / 256, 256, 0, stream>>>(scores, aw);
  k_wsum<<<gE, 256, 0, stream>>>(aw, hseqb, nfbf);

  // ---- GRU ----
  k_mgemm<4><<<dim3(gR, 3), 256, 0, stream>>>(nfbf, wihf, gru_bih, BN_, 24, 0,
                                              gi, 384, nullptr, nullptr, nullptr);
  k_gru<<<gE, 256, 0, stream>>>(gi, gru_bhh, hst, hbf);
  k_proj<<<gW, 256, 0, stream>>>(hst, out_w, out_b, out, 0);

  // ---- graph ODE: one persistent dispatch, 87 device barriers ----
  k_ode<<<PGRID, 256, 0, stream>>>(rp, ev, ow1f, ow2f, ode_b1, ode_b2,
                                   hbf, ubf, t1bf12, rkb, hst,
                                   out_w, out_b, out, xctr, gctr, gflag);
}

// Round 6
// 2120.590 us; speedup vs baseline: 6.4415x; 6.4415x over previous
//
#include <hip/hip_runtime.h>
#include <stdint.h>

#define B_ 4
#define N_ 5000
#define T_ 12
#define FH_ 12
#define H_ 128
#define BN_ 20000
#define E_ 320000
#define TOTE_ (E_ + BN_)

typedef __attribute__((ext_vector_type(8))) short s8v;
typedef __attribute__((ext_vector_type(4))) float f32x4;

__device__ __forceinline__ float fast_tanh(float x) {
  float e = __expf(2.f * x);
  return 1.f - 2.f * __builtin_amdgcn_rcpf(e + 1.f);
}
__device__ __forceinline__ float fast_sigmoid(float x) {
  return __builtin_amdgcn_rcpf(1.f + __expf(-x));
}
__device__ __forceinline__ unsigned short f2bf(float f) {  // RNE
  unsigned u = __float_as_uint(f);
  u = (u + 0x7fffu + ((u >> 16) & 1u)) >> 16;
  return (unsigned short)u;
}
__device__ __forceinline__ float bf2f(unsigned short u) {
  return __uint_as_float(((unsigned)u) << 16);
}
__device__ __forceinline__ unsigned pack2(float lo, float hi) {
  return ((unsigned)f2bf(hi) << 16) | f2bf(lo);
}

__global__ void k_sentinel(float* out) { out[0] = 1e30f; }

__global__ void k_init_cnt(int* cnt) {
  int i = blockIdx.x * 256 + threadIdx.x;
  if (i < BN_) cnt[i] = 1;  // self-loop
}
__global__ void k_count(const int* __restrict__ dst, int* cnt) {
  int e = blockIdx.x * 256 + threadIdx.x;
  if (e < E_) atomicAdd(&cnt[dst[e]], 1);
}
// exclusive scan of cnt -> rp, also dinv[i]=rsqrt(cnt[i]); zeroes cnt
__global__ void k_scan(int* cnt, int* rp, float* dinv) {
  __shared__ int sh[1024];
  int tid = threadIdx.x;
  const int per = (BN_ + 1023) / 1024;
  int start = tid * per;
  int end = start + per; if (end > BN_) end = BN_;
  int s = 0;
  for (int i = start; i < end; i++) {
    int c = cnt[i];
    dinv[i] = rsqrtf((float)c);
    s += c;
  }
  sh[tid] = s;
  __syncthreads();
  for (int off = 1; off < 1024; off <<= 1) {
    int v = (tid >= off) ? sh[tid - off] : 0;
    __syncthreads();
    sh[tid] += v;
    __syncthreads();
  }
  int run = (tid > 0) ? sh[tid - 1] : 0;
  for (int i = start; i < end; i++) {
    int c = cnt[i];
    rp[i] = run;
    run += c;
    cnt[i] = 0;
  }
  if (tid == 1023) rp[BN_] = sh[1023];
}
__global__ void k_fill(const int* __restrict__ src, const int* __restrict__ dst,
                       const int* __restrict__ rp, int* cnt, int2* ev,
                       const float* __restrict__ dinv) {
  int e = blockIdx.x * 256 + threadIdx.x;
  if (e >= TOTE_) return;
  int s, d;
  if (e < E_) { s = src[e]; d = dst[e]; }
  else { s = d = e - E_; }
  int pos = rp[d] + atomicAdd(&cnt[d], 1);
  int2 p; p.x = s; p.y = __float_as_int(dinv[s] * dinv[d]);
  ev[pos] = p;
}

// MFMA B-frag pack: dst[((kc*NT+nt)*64+l)*8+j] = W[kc*32+(l>>4)*8+j][nt*16+(l&15)]
__device__ __forceinline__ void prep_one(const float* __restrict__ src,
                                         unsigned short* __restrict__ dst,
                                         int K, int Nn, int transposed, int idx) {
  int j = idx & 7, l = (idx >> 3) & 63, rest = idx >> 9;
  int NT = Nn >> 4;
  int nt = rest % NT, kc = rest / NT;
  int k = kc * 32 + ((l >> 4) << 3) + j;
  int n = nt * 16 + (l & 15);
  float v = transposed ? src[n * K + k] : src[k * Nn + n];
  dst[idx] = f2bf(v);
}
__global__ void k_prep_all(const float* w2, const float* w3, const float* a1,
                           const float* o1, const float* o2, const float* wih,
                           unsigned short* w2f, unsigned short* w3f, unsigned short* a1f,
                           unsigned short* o1f, unsigned short* o2f, unsigned short* wihf) {
  int idx = blockIdx.x * 256 + threadIdx.x;
  if (idx < 8192) { prep_one(w2, w2f, 64, 128, 0, idx); return; }
  idx -= 8192;
  if (idx < 16384) { prep_one(w3, w3f, 128, 128, 0, idx); return; }
  idx -= 16384;
  if (idx < 16384) { prep_one(a1, a1f, 128, 128, 0, idx); return; }
  idx -= 16384;
  if (idx < 16384) { prep_one(o1, o1f, 128, 128, 0, idx); return; }
  idx -= 16384;
  if (idx < 16384) { prep_one(o2, o2f, 128, 128, 0, idx); return; }
  idx -= 16384;
  if (idx < 49152) prep_one(wih, wihf, 128, 384, 1, idx);
}

// all-T layer1: per row, 12 aggregates + relu(agg*w1+b1) -> h1[t][row][64]
__global__ void k_spl1T(const int* __restrict__ rp, const int2* __restrict__ ev,
                        const float* __restrict__ x,
                        const float* __restrict__ w1, const float* __restrict__ b1,
                        unsigned short* __restrict__ h1) {
  int wid = (blockIdx.x * 256 + threadIdx.x) >> 6;
  int lane = threadIdx.x & 63;
  if (wid >= BN_) return;
  int beg = rp[wid], end = rp[wid + 1];
  float a[12];
#pragma unroll
  for (int t = 0; t < 12; t++) a[t] = 0.f;
  for (int e = beg + lane; e < end; e += 64) {
    int2 p = ev[e];
    const float4* xp = (const float4*)(x + (size_t)p.x * 12);
    float v = __int_as_float(p.y);
    float4 x0 = xp[0], x1 = xp[1], x2 = xp[2];
    a[0] = fmaf(v, x0.x, a[0]);  a[1] = fmaf(v, x0.y, a[1]);
    a[2] = fmaf(v, x0.z, a[2]);  a[3] = fmaf(v, x0.w, a[3]);
    a[4] = fmaf(v, x1.x, a[4]);  a[5] = fmaf(v, x1.y, a[5]);
    a[6] = fmaf(v, x1.z, a[6]);  a[7] = fmaf(v, x1.w, a[7]);
    a[8] = fmaf(v, x2.x, a[8]);  a[9] = fmaf(v, x2.y, a[9]);
    a[10] = fmaf(v, x2.z, a[10]); a[11] = fmaf(v, x2.w, a[11]);
  }
#pragma unroll
  for (int t = 0; t < 12; t++)
#pragma unroll
    for (int m = 1; m < 64; m <<= 1) a[t] += __shfl_xor(a[t], m);
  float wv = w1[lane], bv = b1[lane];
#pragma unroll
  for (int t = 0; t < 12; t++) {
    float v = fmaf(a[t], wv, bv);
    h1[((size_t)t * BN_ + wid) * 64 + lane] = f2bf(fmaxf(v, 0.f));
  }
}

// 4-way edge-split gather: quarter h=l>>4 takes edges [(len*h)>>2,(len*(h+1))>>2),
// lane group c=l&15 covers KIN/16 cols via one 16B(8B) load per edge.
// Combine across quarters with shfl_xor(16),shfl_xor(32). 4 rows per wave (ILP).
template<int KIN>
__device__ __forceinline__ void gather_tile(
    const int* __restrict__ rp, const int2* __restrict__ ev,
    const unsigned short* __restrict__ in, unsigned short (*agg)[KIN + 8],
    int w, int l, int row0g, int nvalid) {
  const int h = l >> 4, c = l & 15;
  constexpr int CW = KIN / 16;  // 8 or 4 cols per lane
  int start[4], len[4];
  float a[4][CW];
  int mx = 0;
#pragma unroll
  for (int r = 0; r < 4; r++) {
    int lr = w * 4 + r;
    bool ok = lr < nvalid;
    int b0 = ok ? rp[row0g + lr] : 0;
    int e0 = ok ? rp[row0g + lr + 1] : 0;
    int ln = ok ? (e0 - b0) : 0;
    int s0 = (ln * h) >> 2, s1 = (ln * (h + 1)) >> 2;
    start[r] = b0 + s0;
    len[r] = s1 - s0;
    mx = len[r] > mx ? len[r] : mx;
#pragma unroll
    for (int q = 0; q < CW; q++) a[r][q] = 0.f;
  }
  for (int i = 0; i < mx; i++) {
#pragma unroll
    for (int r = 0; r < 4; r++) {
      if (i < len[r]) {
        int2 e = ev[start[r] + i];
        float v = __int_as_float(e.y);
        if (KIN == 128) {
          uint4 p = *(const uint4*)(in + (size_t)e.x * 128 + c * 8);
          a[r][0] = fmaf(v, bf2f((unsigned short)(p.x & 0xffffu)), a[r][0]);
          a[r][1] = fmaf(v, bf2f((unsigned short)(p.x >> 16)), a[r][1]);
          a[r][2] = fmaf(v, bf2f((unsigned short)(p.y & 0xffffu)), a[r][2]);
          a[r][3] = fmaf(v, bf2f((unsigned short)(p.y >> 16)), a[r][3]);
          a[r][4] = fmaf(v, bf2f((unsigned short)(p.z & 0xffffu)), a[r][4]);
          a[r][5] = fmaf(v, bf2f((unsigned short)(p.z >> 16)), a[r][5]);
          a[r][6] = fmaf(v, bf2f((unsigned short)(p.w & 0xffffu)), a[r][6]);
          a[r][7] = fmaf(v, bf2f((unsigned short)(p.w >> 16)), a[r][7]);
        } else {
          uint2 p = *(const uint2*)(in + (size_t)e.x * 64 + c * 4);
          a[r][0] = fmaf(v, bf2f((unsigned short)(p.x & 0xffffu)), a[r][0]);
          a[r][1] = fmaf(v, bf2f((unsigned short)(p.x >> 16)), a[r][1]);
          a[r][2] = fmaf(v, bf2f((unsigned short)(p.y & 0xffffu)), a[r][2]);
          a[r][3] = fmaf(v, bf2f((unsigned short)(p.y >> 16)), a[r][3]);
        }
      }
    }
  }
#pragma unroll
  for (int r = 0; r < 4; r++) {
#pragma unroll
    for (int q = 0; q < CW; q++) {
      a[r][q] += __shfl_xor(a[r][q], 16);
      a[r][q] += __shfl_xor(a[r][q], 32);
    }
    if (h == 0) {
      if (KIN == 128) {
        uint4 o;
        o.x = pack2(a[r][0], a[r][1]); o.y = pack2(a[r][2], a[r][3]);
        o.z = pack2(a[r][4], a[r][5]); o.w = pack2(a[r][6], a[r][7]);
        *(uint4*)&agg[w * 4 + r][c * 8] = o;
      } else {
        uint2 o;
        o.x = pack2(a[r][0], a[r][1]); o.y = pack2(a[r][2], a[r][3]);
        *(uint2*)&agg[w * 4 + r][c * 4] = o;
      }
    }
  }
}

template<int KIN>
__device__ __forceinline__ void mfma_tile(
    const unsigned short (*agg)[KIN + 8], const unsigned short* __restrict__ Wf,
    int w, int l, f32x4 acc[2]) {
  constexpr int KC = KIN / 32;
  const int hi = l >> 4, lo16 = l & 15;
  acc[0] = (f32x4){0.f, 0.f, 0.f, 0.f};
  acc[1] = (f32x4){0.f, 0.f, 0.f, 0.f};
#pragma unroll
  for (int kc = 0; kc < KC; kc++) {
    s8v av = *(const s8v*)&agg[lo16][kc * 32 + hi * 8];
#pragma unroll
    for (int q = 0; q < 2; q++) {
      s8v bv = *(const s8v*)(Wf + (((size_t)(kc * 8 + 2 * w + q)) << 9) + (l << 3));
      acc[q] = __builtin_amdgcn_mfma_f32_16x16x32_bf16(av, bv, acc[q], 0, 0, 0);
    }
  }
}

// spatial fused SpMM+GEMM (relu), batched over t = blockIdx.y
template<int KIN>
__global__ __launch_bounds__(256) void k_fusedT(
    const int* __restrict__ rp, const int2* __restrict__ ev,
    const unsigned short* __restrict__ inb, const unsigned short* __restrict__ Wf,
    const float* __restrict__ bias, unsigned short* __restrict__ outb) {
  __shared__ unsigned short agg[16][KIN + 8];
  const int tid = threadIdx.x, l = tid & 63, w = tid >> 6;
  const int t = blockIdx.y;
  const unsigned short* in = inb + (size_t)t * BN_ * KIN;
  unsigned short* out = outb + (size_t)t * BN_ * 128;
  const int bid = blockIdx.x;
  const int xcd = bid & 7, slot = bid >> 3;
  const int bb = xcd >> 1;
  const int within = slot * 2 + (xcd & 1);
  const int wr0 = within * 16;
  int nv = N_ - wr0; nv = nv > 16 ? 16 : nv;
  if (nv <= 0) return;
  const int row0g = bb * N_ + wr0;
  gather_tile<KIN>(rp, ev, in, agg, w, l, row0g, nv);
  __syncthreads();
  f32x4 acc[2];
  mfma_tile<KIN>(agg, Wf, w, l, acc);
  const int hi = l >> 4, lo16 = l & 15;
#pragma unroll
  for (int q = 0; q < 2; q++) {
    int col = (2 * w + q) * 16 + lo16;
    float bi = bias[col];
#pragma unroll
    for (int reg = 0; reg < 4; reg++) {
      int lr = hi * 4 + reg;
      if (lr < nv)
        out[(size_t)(row0g + lr) * 128 + col] = f2bf(fmaxf(acc[q][reg] + bi, 0.f));
    }
  }
}

// ODE fused SpMM+GEMM+epilogue (KIN=128).
// mode 0: outb = bf16(tanh(v))
// mode 1: rkb=bf16(v), ubf=bf16(bf(hbf)+c1*v)
// mode 2: rkb=bf16(bf(rkb)+2v), ubf=bf16(bf(hbf)+c1*v)
// mode 3: h+=c2*(bf(rkb)+v), hbfout=bf16(h), outp[row*FH+step]=dot(h,ow)+ob
__global__ __launch_bounds__(256) void k_fused(
    const int* __restrict__ rp, const int2* __restrict__ ev,
    const unsigned short* __restrict__ in,
    const unsigned short* __restrict__ Wf, const float* __restrict__ bias,
    int mode, float c1, float c2,
    unsigned short* __restrict__ outb,
    const unsigned short* __restrict__ hbfin, unsigned short* __restrict__ rkb,
    float* __restrict__ h, unsigned short* __restrict__ ubfout,
    const float* __restrict__ ow, const float* __restrict__ ob,
    float* __restrict__ outp, int step) {
  __shared__ unsigned short agg[16][136];
  __shared__ float ppart[4][16];
  const int tid = threadIdx.x, l = tid & 63, w = tid >> 6;
  const int bid = blockIdx.x;
  const int xcd = bid & 7, slot = bid >> 3;
  const int bb = xcd >> 1;
  const int within = slot * 2 + (xcd & 1);
  const int wr0 = within * 16;
  int nv = N_ - wr0; nv = nv > 16 ? 16 : (nv < 0 ? 0 : nv);
  const int row0g = bb * N_ + wr0;
  gather_tile<128>(rp, ev, in, agg, w, l, row0g, nv);
  __syncthreads();
  f32x4 acc[2];
  mfma_tile<128>(agg, Wf, w, l, acc);
  const int hi = l >> 4, lo16 = l & 15;
  float p[4] = {0.f, 0.f, 0.f, 0.f};
#pragma unroll
  for (int q = 0; q < 2; q++) {
    int col = (2 * w + q) * 16 + lo16;
    float bi = bias[col];
    float owv = (mode == 3) ? ow[col] : 0.f;
#pragma unroll
    for (int reg = 0; reg < 4; reg++) {
      int lr = hi * 4 + reg;
      if (lr >= nv) continue;
      size_t oi = (size_t)(row0g + lr) * 128 + col;
      float v = fast_tanh(acc[q][reg] + bi);
      if (mode == 0) {
        outb[oi] = f2bf(v);
      } else if (mode == 1) {
        rkb[oi] = f2bf(v);
        ubfout[oi] = f2bf(fmaf(c1, v, bf2f(hbfin[oi])));
      } else if (mode == 2) {
        rkb[oi] = f2bf(bf2f(rkb[oi]) + 2.f * v);
        ubfout[oi] = f2bf(fmaf(c1, v, bf2f(hbfin[oi])));
      } else {
        float nh = fmaf(c2, bf2f(rkb[oi]) + v, h[oi]);
        h[oi] = nh;
        ubfout[oi] = f2bf(nh);
        p[reg] = fmaf(nh, owv, p[reg]);
      }
    }
  }
  if (mode == 3) {
#pragma unroll
    for (int m = 1; m <= 8; m <<= 1)
#pragma unroll
      for (int reg = 0; reg < 4; reg++) p[reg] += __shfl_xor(p[reg], m);
    if (lo16 == 0)
#pragma unroll
      for (int reg = 0; reg < 4; reg++) ppart[w][hi * 4 + reg] = p[reg];
    __syncthreads();
    if (tid < 16 && tid < nv)
      outp[(size_t)(row0g + tid) * FH_ + step] =
          ppart[0][tid] + ppart[1][tid] + ppart[2][tid] + ppart[3][tid] + ob[0];
  }
}

// attention scores: scores[row] = tanh(A[row]@W+b1).w2 + b2  (A = hseqb, T*BN rows)
__global__ __launch_bounds__(256) void k_att(
    const unsigned short* __restrict__ A, const unsigned short* __restrict__ Wf,
    const float* __restrict__ bias, int nrows,
    const float* __restrict__ w2v, const float* __restrict__ b2,
    float* __restrict__ scores) {
  const int tid = threadIdx.x;
  const int l = tid & 63;
  const int w = tid >> 6;
  const int m0 = blockIdx.x * 64 + w * 16;

  f32x4 acc[8];
#pragma unroll
  for (int nt = 0; nt < 8; nt++) acc[nt] = (f32x4){0.f, 0.f, 0.f, 0.f};
  int arow = m0 + (l & 15);
  if (arow >= nrows) arow = nrows - 1;
  const unsigned short* Ap = A + (size_t)arow * 128 + ((l >> 4) << 3);
#pragma unroll
  for (int kc = 0; kc < 4; kc++) {
    s8v av = *(const s8v*)(Ap + kc * 32);
#pragma unroll
    for (int nt = 0; nt < 8; nt++) {
      s8v bv = *(const s8v*)(Wf + (((size_t)(kc * 8 + nt)) << 9) + (l << 3));
      acc[nt] = __builtin_amdgcn_mfma_f32_16x16x32_bf16(av, bv, acc[nt], 0, 0, 0);
    }
  }
  float p[4] = {0.f, 0.f, 0.f, 0.f};
#pragma unroll
  for (int nt = 0; nt < 8; nt++) {
    int col = nt * 16 + (l & 15);
    float bi = bias[col], wv = w2v[col];
#pragma unroll
    for (int reg = 0; reg < 4; reg++)
      p[reg] = fmaf(fast_tanh(acc[nt][reg] + bi), wv, p[reg]);
  }
#pragma unroll
  for (int m = 1; m <= 8; m <<= 1)
#pragma unroll
    for (int reg = 0; reg < 4; reg++) p[reg] += __shfl_xor(p[reg], m);
  if ((l & 15) == 0) {
    float bb = b2[0];
#pragma unroll
    for (int reg = 0; reg < 4; reg++) {
      int row = m0 + ((l >> 4) << 2) + reg;
      if (row < nrows) scores[row] = p[reg] + bb;
    }
  }
}

// fused softmax + weighted sum: nf[bn][:] = sum_t softmax_t(sc)[bn] * hs[t][bn][:]
__global__ void k_attw(const float* __restrict__ sc, const unsigned short* __restrict__ hs,
                       unsigned short* __restrict__ nf) {
  int idx = blockIdx.x * 256 + threadIdx.x;
  if (idx >= BN_ * 64) return;
  int bn = idx >> 6, c = idx & 63;
  float v[T_];
  float m = -1e30f;
#pragma unroll
  for (int t = 0; t < T_; t++) { v[t] = sc[t * BN_ + bn]; m = fmaxf(m, v[t]); }
  float ssum = 0.f;
#pragma unroll
  for (int t = 0; t < T_; t++) { v[t] = __expf(v[t] - m); ssum += v[t]; }
  float inv = __builtin_amdgcn_rcpf(ssum);
  float s0 = 0.f, s1 = 0.f;
#pragma unroll
  for (int t = 0; t < T_; t++) {
    unsigned p = *(const unsigned*)(hs + ((size_t)t * BN_ + bn) * 128 + c * 2);
    float aw = v[t] * inv;
    s0 = fmaf(aw, bf2f((unsigned short)(p & 0xffffu)), s0);
    s1 = fmaf(aw, bf2f((unsigned short)(p >> 16)), s1);
  }
  *(unsigned*)(nf + (size_t)bn * 128 + c * 2) = pack2(s0, s1);
}

// fused GRU: full 384-col GEMM per wave (24 frags) + gate math + step-0 projection
__global__ __launch_bounds__(256) void k_gruf(
    const unsigned short* __restrict__ A, const unsigned short* __restrict__ Wf,
    const float* __restrict__ bih, const float* __restrict__ bhh,
    float* __restrict__ hst, unsigned short* __restrict__ hbf,
    const float* __restrict__ ow, const float* __restrict__ ob,
    float* __restrict__ outp) {
  const int tid = threadIdx.x;
  const int l = tid & 63;
  const int w = tid >> 6;
  const int m0 = blockIdx.x * 64 + w * 16;

  f32x4 acc[24];
#pragma unroll
  for (int nt = 0; nt < 24; nt++) acc[nt] = (f32x4){0.f, 0.f, 0.f, 0.f};
  int arow = m0 + (l & 15);
  if (arow >= BN_) arow = BN_ - 1;
  const unsigned short* Ap = A + (size_t)arow * 128 + ((l >> 4) << 3);
#pragma unroll
  for (int kc = 0; kc < 4; kc++) {
    s8v av = *(const s8v*)(Ap + kc * 32);
#pragma unroll
    for (int nt = 0; nt < 24; nt++) {
      s8v bv = *(const s8v*)(Wf + (((size_t)(kc * 24 + nt)) << 9) + (l << 3));
      acc[nt] = __builtin_amdgcn_mfma_f32_16x16x32_bf16(av, bv, acc[nt], 0, 0, 0);
    }
  }
  const int hi = l >> 4, lo16 = l & 15;
  float p[4] = {0.f, 0.f, 0.f, 0.f};
#pragma unroll
  for (int nt = 0; nt < 8; nt++) {
    int col = nt * 16 + lo16;
    float br = bih[col], bz = bih[col + 128], bn = bih[col + 256];
    float hr = bhh[col], hz = bhh[col + 128], hn = bhh[col + 256];
    float owv = ow[col];
#pragma unroll
    for (int reg = 0; reg < 4; reg++) {
      int row = m0 + hi * 4 + reg;
      if (row >= BN_) continue;
      float r = fast_sigmoid(acc[nt][reg] + br + hr);
      float z = fast_sigmoid(acc[nt + 8][reg] + bz + hz);
      float n = fast_tanh(acc[nt + 16][reg] + bn + r * hn);
      float hv = (1.f - z) * n;  // h0 = 0
      size_t oi = (size_t)row * 128 + col;
      hst[oi] = hv;
      hbf[oi] = f2bf(hv);
      p[reg] = fmaf(hv, owv, p[reg]);
    }
  }
#pragma unroll
  for (int m = 1; m <= 8; m <<= 1)
#pragma unroll
    for (int reg = 0; reg < 4; reg++) p[reg] += __shfl_xor(p[reg], m);
  if (lo16 == 0) {
    float obv = ob[0];
#pragma unroll
    for (int reg = 0; reg < 4; reg++) {
      int row = m0 + hi * 4 + reg;
      if (row < BN_) outp[(size_t)row * FH_ + 0] = p[reg] + obv;
    }
  }
}

extern "C" void kernel_launch(void* const* d_in, const int* in_sizes, int n_in,
                              void* d_out, int out_size, void* d_ws, size_t ws_size,
                              hipStream_t stream) {
  const float* x       = (const float*)d_in[0];
  const float* gcn_w1  = (const float*)d_in[1];
  const float* gcn_b1  = (const float*)d_in[2];
  const float* gcn_w2  = (const float*)d_in[3];
  const float* gcn_b2  = (const float*)d_in[4];
  const float* gcn_w3  = (const float*)d_in[5];
  const float* gcn_b3  = (const float*)d_in[6];
  const float* att_w1  = (const float*)d_in[7];
  const float* att_b1  = (const float*)d_in[8];
  const float* att_w2  = (const float*)d_in[9];
  const float* att_b2  = (const float*)d_in[10];
  const float* gru_wih = (const float*)d_in[11];
  const float* gru_bih = (const float*)d_in[13];
  const float* gru_bhh = (const float*)d_in[14];
  const float* ode_w1  = (const float*)d_in[15];
  const float* ode_b1  = (const float*)d_in[16];
  const float* ode_w2  = (const float*)d_in[17];
  const float* ode_b2  = (const float*)d_in[18];
  const float* out_w   = (const float*)d_in[19];
  const float* out_b   = (const float*)d_in[20];
  const int*   eidx    = (const int*)d_in[21];
  float* out = (float*)d_out;

  float* wsf = (float*)d_ws;
  size_t off = 0;
  unsigned short* h1b12 = (unsigned short*)(wsf + off); off += (size_t)BN_ * 384;  // 12*BN*64 bf16
  float* hst    = wsf + off; off += (size_t)BN_ * H_;
  float* scores = wsf + off; off += (size_t)T_ * BN_;
  float* dinv   = wsf + off; off += BN_;
  int2*  ev     = (int2*)(wsf + off); off += (size_t)TOTE_ * 2;
  unsigned short* hseqb  = (unsigned short*)(wsf + off); off += (size_t)T_ * BN_ * H_ / 2;
  unsigned short* t1b12  = (unsigned short*)(wsf + off); off += (size_t)T_ * BN_ * H_ / 2;
  unsigned short* hbf    = (unsigned short*)(wsf + off); off += (size_t)BN_ * H_ / 2;
  unsigned short* ubf    = (unsigned short*)(wsf + off); off += (size_t)BN_ * H_ / 2;
  unsigned short* rkb    = (unsigned short*)(wsf + off); off += (size_t)BN_ * H_ / 2;
  unsigned short* nfbf   = (unsigned short*)(wsf + off); off += (size_t)BN_ * H_ / 2;
  unsigned short* w2f    = (unsigned short*)(wsf + off); off += 64 * 128 / 2;
  unsigned short* w3f    = (unsigned short*)(wsf + off); off += 128 * 128 / 2;
  unsigned short* aw1f   = (unsigned short*)(wsf + off); off += 128 * 128 / 2;
  unsigned short* ow1f   = (unsigned short*)(wsf + off); off += 128 * 128 / 2;
  unsigned short* ow2f   = (unsigned short*)(wsf + off); off += 128 * 128 / 2;
  unsigned short* wihf   = (unsigned short*)(wsf + off); off += 128 * 384 / 2;
  int* rp  = (int*)(wsf + off); off += BN_ + 1;
  int* cnt = (int*)(wsf + off); off += BN_;
  if (ws_size < off * sizeof(float)) {
    k_sentinel<<<1, 1, 0, stream>>>(out);
    return;
  }

  const int* esrc = eidx;
  const int* edst = eidx + E_;

  // ---- CSR build + weight prep ----
  k_init_cnt<<<(BN_ + 255) / 256, 256, 0, stream>>>(cnt);
  k_count<<<(E_ + 255) / 256, 256, 0, stream>>>(edst, cnt);
  k_scan<<<1, 1024, 0, stream>>>(cnt, rp, dinv);
  k_fill<<<(TOTE_ + 255) / 256, 256, 0, stream>>>(esrc, edst, rp, cnt, ev, dinv);
  k_prep_all<<<480, 256, 0, stream>>>(gcn_w2, gcn_w3, att_w1, ode_w1, ode_w2, gru_wih,
                                      w2f, w3f, aw1f, ow1f, ow2f, wihf);

  const int gW = BN_ / 4;
  const int gR = (BN_ + 63) / 64;
  const int gF = 1280;

  // ---- spatial encoder: 3 dispatches for all 12 timesteps ----
  k_spl1T<<<gW, 256, 0, stream>>>(rp, ev, x, gcn_w1, gcn_b1, h1b12);
  k_fusedT<64><<<dim3(gF, 12), 256, 0, stream>>>(rp, ev, h1b12, w2f, gcn_b2, t1b12);
  k_fusedT<128><<<dim3(gF, 12), 256, 0, stream>>>(rp, ev, t1b12, w3f, gcn_b3, hseqb);

  // ---- temporal attention ----
  k_att<<<(T_ * BN_ + 63) / 64, 256, 0, stream>>>(hseqb, aw1f, att_b1, T_ * BN_,
                                                  att_w2, att_b2, scores);
  k_attw<<<(BN_ * 64 + 255) / 256, 256, 0, stream>>>(scores, hseqb, nfbf);

  // ---- GRU (fused GEMM + gates + step-0 projection) ----
  k_gruf<<<gR, 256, 0, stream>>>(nfbf, wihf, gru_bih, gru_bhh, hst, hbf,
                                 out_w, out_b, out);

  // ---- graph ODE, RK4: 2 fused dispatches per f-eval ----
  const float dt = (float)FH_ / (float)(FH_ - 1);
  unsigned short* t1 = t1b12;  // reuse first BN*128 of spatial scratch
  auto f_eval = [&](const unsigned short* inbf, int mode, float c1, float c2, int step) {
    k_fused<<<gF, 256, 0, stream>>>(rp, ev, inbf, ow1f, ode_b1, 0, 0.f, 0.f,
                                    t1, nullptr, nullptr, nullptr, nullptr,
                                    nullptr, nullptr, nullptr, 0);
    k_fused<<<gF, 256, 0, stream>>>(rp, ev, t1, ow2f, ode_b2, mode, c1, c2,
                                    nullptr, hbf, rkb, hst,
                                    (mode == 3) ? hbf : ubf,
                                    out_w, out_b, out, step);
  };
  for (int s = 1; s < FH_; s++) {
    f_eval(hbf, 1, 0.5f * dt, 0.f, s);
    f_eval(ubf, 2, 0.5f * dt, 0.f, s);
    f_eval(ubf, 2, dt, 0.f, s);
    f_eval(ubf, 3, 0.f, dt / 6.f, s);
  }
}

// Round 7
// 2047.629 us; speedup vs baseline: 6.6711x; 1.0356x over previous
//
#include <hip/hip_runtime.h>
#include <stdint.h>

#define B_ 4
#define N_ 5000
#define T_ 12
#define FH_ 12
#define H_ 128
#define BN_ 20000
#define E_ 320000
#define TOTE_ (E_ + BN_)
#define EVCAP_ (TOTE_ + BN_)   // room for even-alignment pads

typedef __attribute__((ext_vector_type(8))) short s8v;
typedef __attribute__((ext_vector_type(4))) float f32x4;

__device__ __forceinline__ float fast_tanh(float x) {
  float e = __expf(2.f * x);
  return 1.f - 2.f * __builtin_amdgcn_rcpf(e + 1.f);
}
__device__ __forceinline__ float fast_sigmoid(float x) {
  return __builtin_amdgcn_rcpf(1.f + __expf(-x));
}
__device__ __forceinline__ unsigned short f2bf(float f) {  // RNE
  unsigned u = __float_as_uint(f);
  u = (u + 0x7fffu + ((u >> 16) & 1u)) >> 16;
  return (unsigned short)u;
}
__device__ __forceinline__ float bf2f(unsigned short u) {
  return __uint_as_float(((unsigned)u) << 16);
}
__device__ __forceinline__ unsigned pack2(float lo, float hi) {
  return ((unsigned)f2bf(hi) << 16) | f2bf(lo);
}

__global__ void k_sentinel(float* out) { out[0] = 1e30f; }

__global__ void k_init_cnt(int* cnt) {
  int i = blockIdx.x * 256 + threadIdx.x;
  if (i < BN_) cnt[i] = 1;  // self-loop
}
__global__ void k_count(const int* __restrict__ dst, int* cnt) {
  int e = blockIdx.x * 256 + threadIdx.x;
  if (e < E_) atomicAdd(&cnt[dst[e]], 1);
}
// exclusive scan of cnt -> rp (row starts EVEN-aligned), dinv=rsqrt(cnt); zero cnt
__global__ void k_scan(int* cnt, int* rp, float* dinv) {
  __shared__ int sh[1024];
  int tid = threadIdx.x;
  const int per = (BN_ + 1023) / 1024;
  int start = tid * per;
  int end = start + per; if (end > BN_) end = BN_;
  int s = 0;
  for (int i = start; i < end; i++) {
    int c = cnt[i];
    dinv[i] = rsqrtf((float)c);
    s += (c + 1) & ~1;  // padded length
  }
  sh[tid] = s;
  __syncthreads();
  for (int off = 1; off < 1024; off <<= 1) {
    int v = (tid >= off) ? sh[tid - off] : 0;
    __syncthreads();
    sh[tid] += v;
    __syncthreads();
  }
  int run = (tid > 0) ? sh[tid - 1] : 0;
  for (int i = start; i < end; i++) {
    int c = cnt[i];
    rp[i] = run;
    run += (c + 1) & ~1;
    cnt[i] = 0;
  }
  if (tid == 1023) rp[BN_] = sh[1023];
}
// ev[pos] = {src*128, bits(dinv[s]*dinv[d])}; pad slots stay zero (memset)
__global__ void k_fill(const int* __restrict__ src, const int* __restrict__ dst,
                       const int* __restrict__ rp, int* cnt, int2* ev,
                       const float* __restrict__ dinv) {
  int e = blockIdx.x * 256 + threadIdx.x;
  if (e >= TOTE_) return;
  int s, d;
  if (e < E_) { s = src[e]; d = dst[e]; }
  else { s = d = e - E_; }
  int pos = rp[d] + atomicAdd(&cnt[d], 1);
  int2 p; p.x = s * 128; p.y = __float_as_int(dinv[s] * dinv[d]);
  ev[pos] = p;
}

// ---- degree sort (per batch) ----
__global__ void k_hist(const int* __restrict__ rp, int* hist) {
  int i = blockIdx.x * 256 + threadIdx.x;
  if (i < BN_) {
    int d = rp[i + 1] - rp[i]; d = d > 63 ? 63 : d;
    atomicAdd(&hist[(i / N_) * 64 + d], 1);
  }
}
__global__ void k_binscan(int* hist) {  // 256 bins -> exclusive base (in place)
  __shared__ int sh[256];
  int t = threadIdx.x;
  int val = hist[t];
  sh[t] = val;
  __syncthreads();
  for (int o = 1; o < 256; o <<= 1) {
    int v = (t >= o) ? sh[t - o] : 0;
    __syncthreads();
    sh[t] += v;
    __syncthreads();
  }
  hist[t] = sh[t] - val;  // exclusive; becomes running counter
}
__global__ void k_scatter(const int* __restrict__ rp, int* hist, int* ord) {
  int i = blockIdx.x * 256 + threadIdx.x;
  if (i < BN_) {
    int d = rp[i + 1] - rp[i]; d = d > 63 ? 63 : d;
    int pos = atomicAdd(&hist[(i / N_) * 64 + d], 1);
    ord[pos] = i;
  }
}

// MFMA B-frag pack
__device__ __forceinline__ void prep_one(const float* __restrict__ src,
                                         unsigned short* __restrict__ dst,
                                         int K, int Nn, int transposed, int idx) {
  int j = idx & 7, l = (idx >> 3) & 63, rest = idx >> 9;
  int NT = Nn >> 4;
  int nt = rest % NT, kc = rest / NT;
  int k = kc * 32 + ((l >> 4) << 3) + j;
  int n = nt * 16 + (l & 15);
  float v = transposed ? src[n * K + k] : src[k * Nn + n];
  dst[idx] = f2bf(v);
}
__global__ void k_prep_all(const float* w2, const float* w3, const float* a1,
                           const float* o1, const float* o2, const float* wih,
                           unsigned short* w2f, unsigned short* w3f, unsigned short* a1f,
                           unsigned short* o1f, unsigned short* o2f, unsigned short* wihf) {
  int idx = blockIdx.x * 256 + threadIdx.x;
  if (idx < 8192) { prep_one(w2, w2f, 64, 128, 0, idx); return; }
  idx -= 8192;
  if (idx < 16384) { prep_one(w3, w3f, 128, 128, 0, idx); return; }
  idx -= 16384;
  if (idx < 16384) { prep_one(a1, a1f, 128, 128, 0, idx); return; }
  idx -= 16384;
  if (idx < 16384) { prep_one(o1, o1f, 128, 128, 0, idx); return; }
  idx -= 16384;
  if (idx < 16384) { prep_one(o2, o2f, 128, 128, 0, idx); return; }
  idx -= 16384;
  if (idx < 49152) prep_one(wih, wihf, 128, 384, 1, idx);
}

// all-T layer1
__global__ void k_spl1T(const int* __restrict__ rp, const int2* __restrict__ ev,
                        const float* __restrict__ x,
                        const float* __restrict__ w1, const float* __restrict__ b1,
                        unsigned short* __restrict__ h1) {
  int wid = (blockIdx.x * 256 + threadIdx.x) >> 6;
  int lane = threadIdx.x & 63;
  if (wid >= BN_) return;
  int beg = rp[wid], end = rp[wid + 1];
  float a[12];
#pragma unroll
  for (int t = 0; t < 12; t++) a[t] = 0.f;
  for (int e = beg + lane; e < end; e += 64) {
    int2 p = ev[e];
    const float4* xp = (const float4*)(x + (size_t)(p.x >> 7) * 12);
    float v = __int_as_float(p.y);
    float4 x0 = xp[0], x1 = xp[1], x2 = xp[2];
    a[0] = fmaf(v, x0.x, a[0]);  a[1] = fmaf(v, x0.y, a[1]);
    a[2] = fmaf(v, x0.z, a[2]);  a[3] = fmaf(v, x0.w, a[3]);
    a[4] = fmaf(v, x1.x, a[4]);  a[5] = fmaf(v, x1.y, a[5]);
    a[6] = fmaf(v, x1.z, a[6]);  a[7] = fmaf(v, x1.w, a[7]);
    a[8] = fmaf(v, x2.x, a[8]);  a[9] = fmaf(v, x2.y, a[9]);
    a[10] = fmaf(v, x2.z, a[10]); a[11] = fmaf(v, x2.w, a[11]);
  }
#pragma unroll
  for (int t = 0; t < 12; t++)
#pragma unroll
    for (int m = 1; m < 64; m <<= 1) a[t] += __shfl_xor(a[t], m);
  float wv = w1[lane], bv = b1[lane];
#pragma unroll
  for (int t = 0; t < 12; t++) {
    float v = fmaf(a[t], wv, bv);
    h1[((size_t)t * BN_ + wid) * 64 + lane] = f2bf(fmaxf(v, 0.f));
  }
}

// pair-processed 4-way edge-split gather; rows come from ordt[] (degree-sorted)
template<int KIN>
__device__ __forceinline__ void gather_tile(
    const int* __restrict__ rp, const int2* __restrict__ ev,
    const unsigned short* __restrict__ in, unsigned short (*agg)[KIN + 8],
    const int* __restrict__ ordt, int w, int l, int nvalid) {
  const int h = l >> 4, c = l & 15;
  constexpr int CW = KIN / 16;
  const unsigned short* inc = in + c * CW;
  int st[4], len[4];
  float a[4][CW];
  int mx = 0;
#pragma unroll
  for (int r = 0; r < 4; r++) {
    int lr = w * 4 + r;
    bool ok = lr < nvalid;
    int row = ok ? ordt[lr] : 0;
    int b0 = ok ? rp[row] : 0;
    int e0 = ok ? rp[row + 1] : 0;
    int np = (e0 - b0) >> 1;            // pairs (rows even-aligned)
    int p0 = (np * h) >> 2, p1 = (np * (h + 1)) >> 2;
    st[r] = (b0 >> 1) + p0;
    len[r] = p1 - p0;
    mx = len[r] > mx ? len[r] : mx;
#pragma unroll
    for (int q = 0; q < CW; q++) a[r][q] = 0.f;
  }
  const int4* evp = (const int4*)ev;    // 2 edges per load (16B aligned)
  for (int i = 0; i < mx; i++) {
#pragma unroll
    for (int r = 0; r < 4; r++) {
      if (i < len[r]) {
        int4 q = evp[st[r] + i];
        float v0 = __int_as_float(q.y), v1 = __int_as_float(q.w);
        if (KIN == 128) {
          uint4 pA = *(const uint4*)(inc + q.x);
          uint4 pB = *(const uint4*)(inc + q.z);
          a[r][0] = fmaf(v0, bf2f((unsigned short)(pA.x & 0xffffu)), a[r][0]);
          a[r][1] = fmaf(v0, bf2f((unsigned short)(pA.x >> 16)), a[r][1]);
          a[r][2] = fmaf(v0, bf2f((unsigned short)(pA.y & 0xffffu)), a[r][2]);
          a[r][3] = fmaf(v0, bf2f((unsigned short)(pA.y >> 16)), a[r][3]);
          a[r][4] = fmaf(v0, bf2f((unsigned short)(pA.z & 0xffffu)), a[r][4]);
          a[r][5] = fmaf(v0, bf2f((unsigned short)(pA.z >> 16)), a[r][5]);
          a[r][6] = fmaf(v0, bf2f((unsigned short)(pA.w & 0xffffu)), a[r][6]);
          a[r][7] = fmaf(v0, bf2f((unsigned short)(pA.w >> 16)), a[r][7]);
          a[r][0] = fmaf(v1, bf2f((unsigned short)(pB.x & 0xffffu)), a[r][0]);
          a[r][1] = fmaf(v1, bf2f((unsigned short)(pB.x >> 16)), a[r][1]);
          a[r][2] = fmaf(v1, bf2f((unsigned short)(pB.y & 0xffffu)), a[r][2]);
          a[r][3] = fmaf(v1, bf2f((unsigned short)(pB.y >> 16)), a[r][3]);
          a[r][4] = fmaf(v1, bf2f((unsigned short)(pB.z & 0xffffu)), a[r][4]);
          a[r][5] = fmaf(v1, bf2f((unsigned short)(pB.z >> 16)), a[r][5]);
          a[r][6] = fmaf(v1, bf2f((unsigned short)(pB.w & 0xffffu)), a[r][6]);
          a[r][7] = fmaf(v1, bf2f((unsigned short)(pB.w >> 16)), a[r][7]);
        } else {
          uint2 pA = *(const uint2*)(inc + (q.x >> 1));
          uint2 pB = *(const uint2*)(inc + (q.z >> 1));
          a[r][0] = fmaf(v0, bf2f((unsigned short)(pA.x & 0xffffu)), a[r][0]);
          a[r][1] = fmaf(v0, bf2f((unsigned short)(pA.x >> 16)), a[r][1]);
          a[r][2] = fmaf(v0, bf2f((unsigned short)(pA.y & 0xffffu)), a[r][2]);
          a[r][3] = fmaf(v0, bf2f((unsigned short)(pA.y >> 16)), a[r][3]);
          a[r][0] = fmaf(v1, bf2f((unsigned short)(pB.x & 0xffffu)), a[r][0]);
          a[r][1] = fmaf(v1, bf2f((unsigned short)(pB.x >> 16)), a[r][1]);
          a[r][2] = fmaf(v1, bf2f((unsigned short)(pB.y & 0xffffu)), a[r][2]);
          a[r][3] = fmaf(v1, bf2f((unsigned short)(pB.y >> 16)), a[r][3]);
        }
      }
    }
  }
#pragma unroll
  for (int r = 0; r < 4; r++) {
#pragma unroll
    for (int q = 0; q < CW; q++) {
      a[r][q] += __shfl_xor(a[r][q], 16);
      a[r][q] += __shfl_xor(a[r][q], 32);
    }
    if (h == 0) {
      if (KIN == 128) {
        uint4 o;
        o.x = pack2(a[r][0], a[r][1]); o.y = pack2(a[r][2], a[r][3]);
        o.z = pack2(a[r][4], a[r][5]); o.w = pack2(a[r][6], a[r][7]);
        *(uint4*)&agg[w * 4 + r][c * 8] = o;
      } else {
        uint2 o;
        o.x = pack2(a[r][0], a[r][1]); o.y = pack2(a[r][2], a[r][3]);
        *(uint2*)&agg[w * 4 + r][c * 4] = o;
      }
    }
  }
}

template<int KIN>
__device__ __forceinline__ void mfma_tile(
    const unsigned short (*agg)[KIN + 8], const unsigned short* __restrict__ Wf,
    int w, int l, f32x4 acc[2]) {
  constexpr int KC = KIN / 32;
  const int hi = l >> 4, lo16 = l & 15;
  acc[0] = (f32x4){0.f, 0.f, 0.f, 0.f};
  acc[1] = (f32x4){0.f, 0.f, 0.f, 0.f};
#pragma unroll
  for (int kc = 0; kc < KC; kc++) {
    s8v av = *(const s8v*)&agg[lo16][kc * 32 + hi * 8];
#pragma unroll
    for (int q = 0; q < 2; q++) {
      s8v bv = *(const s8v*)(Wf + (((size_t)(kc * 8 + 2 * w + q)) << 9) + (l << 3));
      acc[q] = __builtin_amdgcn_mfma_f32_16x16x32_bf16(av, bv, acc[q], 0, 0, 0);
    }
  }
}

// spatial fused SpMM+GEMM (relu), batched over t = blockIdx.y
template<int KIN>
__global__ __launch_bounds__(256) void k_fusedT(
    const int* __restrict__ rp, const int2* __restrict__ ev,
    const int* __restrict__ ord,
    const unsigned short* __restrict__ inb, const unsigned short* __restrict__ Wf,
    const float* __restrict__ bias, unsigned short* __restrict__ outb) {
  __shared__ unsigned short agg[16][KIN + 8];
  const int tid = threadIdx.x, l = tid & 63, w = tid >> 6;
  const int t = blockIdx.y;
  const unsigned short* in = inb + (size_t)t * BN_ * KIN;
  unsigned short* out = outb + (size_t)t * BN_ * 128;
  const int bid = blockIdx.x;
  const int xcd = bid & 7, slot = bid >> 3;
  const int bb = xcd >> 1;
  const int within = slot * 2 + (xcd & 1);
  const int wr0 = within * 16;
  int nv = N_ - wr0; nv = nv > 16 ? 16 : nv;
  if (nv <= 0) return;
  const int* ordt = ord + bb * N_ + wr0;
  gather_tile<KIN>(rp, ev, in, agg, ordt, w, l, nv);
  __syncthreads();
  f32x4 acc[2];
  mfma_tile<KIN>(agg, Wf, w, l, acc);
  const int hi = l >> 4, lo16 = l & 15;
#pragma unroll
  for (int q = 0; q < 2; q++) {
    int col = (2 * w + q) * 16 + lo16;
    float bi = bias[col];
#pragma unroll
    for (int reg = 0; reg < 4; reg++) {
      int lr = hi * 4 + reg;
      if (lr < nv) {
        int grow = ordt[lr];
        out[(size_t)grow * 128 + col] = f2bf(fmaxf(acc[q][reg] + bi, 0.f));
      }
    }
  }
}

// ODE fused SpMM+GEMM+epilogue (KIN=128), modes as before
__global__ __launch_bounds__(256) void k_fused(
    const int* __restrict__ rp, const int2* __restrict__ ev,
    const int* __restrict__ ord,
    const unsigned short* __restrict__ in,
    const unsigned short* __restrict__ Wf, const float* __restrict__ bias,
    int mode, float c1, float c2,
    unsigned short* __restrict__ outb,
    const unsigned short* __restrict__ hbfin, unsigned short* __restrict__ rkb,
    float* __restrict__ h, unsigned short* __restrict__ ubfout,
    const float* __restrict__ ow, const float* __restrict__ ob,
    float* __restrict__ outp, int step) {
  __shared__ unsigned short agg[16][136];
  __shared__ float ppart[4][16];
  const int tid = threadIdx.x, l = tid & 63, w = tid >> 6;
  const int bid = blockIdx.x;
  const int xcd = bid & 7, slot = bid >> 3;
  const int bb = xcd >> 1;
  const int within = slot * 2 + (xcd & 1);
  const int wr0 = within * 16;
  int nv = N_ - wr0; nv = nv > 16 ? 16 : (nv < 0 ? 0 : nv);
  if (nv <= 0) return;
  const int* ordt = ord + bb * N_ + wr0;
  gather_tile<128>(rp, ev, in, agg, ordt, w, l, nv);
  __syncthreads();
  f32x4 acc[2];
  mfma_tile<128>(agg, Wf, w, l, acc);
  const int hi = l >> 4, lo16 = l & 15;
  float p[4] = {0.f, 0.f, 0.f, 0.f};
#pragma unroll
  for (int q = 0; q < 2; q++) {
    int col = (2 * w + q) * 16 + lo16;
    float bi = bias[col];
    float owv = (mode == 3) ? ow[col] : 0.f;
#pragma unroll
    for (int reg = 0; reg < 4; reg++) {
      int lr = hi * 4 + reg;
      if (lr >= nv) continue;
      int grow = ordt[lr];
      size_t oi = (size_t)grow * 128 + col;
      float v = fast_tanh(acc[q][reg] + bi);
      if (mode == 0) {
        outb[oi] = f2bf(v);
      } else if (mode == 1) {
        rkb[oi] = f2bf(v);
        ubfout[oi] = f2bf(fmaf(c1, v, bf2f(hbfin[oi])));
      } else if (mode == 2) {
        rkb[oi] = f2bf(bf2f(rkb[oi]) + 2.f * v);
        ubfout[oi] = f2bf(fmaf(c1, v, bf2f(hbfin[oi])));
      } else {
        float nh = fmaf(c2, bf2f(rkb[oi]) + v, h[oi]);
        h[oi] = nh;
        ubfout[oi] = f2bf(nh);
        p[reg] = fmaf(nh, owv, p[reg]);
      }
    }
  }
  if (mode == 3) {
#pragma unroll
    for (int m = 1; m <= 8; m <<= 1)
#pragma unroll
      for (int reg = 0; reg < 4; reg++) p[reg] += __shfl_xor(p[reg], m);
    if (lo16 == 0)
#pragma unroll
      for (int reg = 0; reg < 4; reg++) ppart[w][hi * 4 + reg] = p[reg];
    __syncthreads();
    if (tid < 16 && tid < nv) {
      int grow = ordt[tid];
      outp[(size_t)grow * FH_ + step] =
          ppart[0][tid] + ppart[1][tid] + ppart[2][tid] + ppart[3][tid] + ob[0];
    }
  }
}

// attention scores
__global__ __launch_bounds__(256) void k_att(
    const unsigned short* __restrict__ A, const unsigned short* __restrict__ Wf,
    const float* __restrict__ bias, int nrows,
    const float* __restrict__ w2v, const float* __restrict__ b2,
    float* __restrict__ scores) {
  const int tid = threadIdx.x;
  const int l = tid & 63;
  const int w = tid >> 6;
  const int m0 = blockIdx.x * 64 + w * 16;

  f32x4 acc[8];
#pragma unroll
  for (int nt = 0; nt < 8; nt++) acc[nt] = (f32x4){0.f, 0.f, 0.f, 0.f};
  int arow = m0 + (l & 15);
  if (arow >= nrows) arow = nrows - 1;
  const unsigned short* Ap = A + (size_t)arow * 128 + ((l >> 4) << 3);
#pragma unroll
  for (int kc = 0; kc < 4; kc++) {
    s8v av = *(const s8v*)(Ap + kc * 32);
#pragma unroll
    for (int nt = 0; nt < 8; nt++) {
      s8v bv = *(const s8v*)(Wf + (((size_t)(kc * 8 + nt)) << 9) + (l << 3));
      acc[nt] = __builtin_amdgcn_mfma_f32_16x16x32_bf16(av, bv, acc[nt], 0, 0, 0);
    }
  }
  float p[4] = {0.f, 0.f, 0.f, 0.f};
#pragma unroll
  for (int nt = 0; nt < 8; nt++) {
    int col = nt * 16 + (l & 15);
    float bi = bias[col], wv = w2v[col];
#pragma unroll
    for (int reg = 0; reg < 4; reg++)
      p[reg] = fmaf(fast_tanh(acc[nt][reg] + bi), wv, p[reg]);
  }
#pragma unroll
  for (int m = 1; m <= 8; m <<= 1)
#pragma unroll
    for (int reg = 0; reg < 4; reg++) p[reg] += __shfl_xor(p[reg], m);
  if ((l & 15) == 0) {
    float bb = b2[0];
#pragma unroll
    for (int reg = 0; reg < 4; reg++) {
      int row = m0 + ((l >> 4) << 2) + reg;
      if (row < nrows) scores[row] = p[reg] + bb;
    }
  }
}

// fused softmax + weighted sum
__global__ void k_attw(const float* __restrict__ sc, const unsigned short* __restrict__ hs,
                       unsigned short* __restrict__ nf) {
  int idx = blockIdx.x * 256 + threadIdx.x;
  if (idx >= BN_ * 64) return;
  int bn = idx >> 6, c = idx & 63;
  float v[T_];
  float m = -1e30f;
#pragma unroll
  for (int t = 0; t < T_; t++) { v[t] = sc[t * BN_ + bn]; m = fmaxf(m, v[t]); }
  float ssum = 0.f;
#pragma unroll
  for (int t = 0; t < T_; t++) { v[t] = __expf(v[t] - m); ssum += v[t]; }
  float inv = __builtin_amdgcn_rcpf(ssum);
  float s0 = 0.f, s1 = 0.f;
#pragma unroll
  for (int t = 0; t < T_; t++) {
    unsigned p = *(const unsigned*)(hs + ((size_t)t * BN_ + bn) * 128 + c * 2);
    float aw = v[t] * inv;
    s0 = fmaf(aw, bf2f((unsigned short)(p & 0xffffu)), s0);
    s1 = fmaf(aw, bf2f((unsigned short)(p >> 16)), s1);
  }
  *(unsigned*)(nf + (size_t)bn * 128 + c * 2) = pack2(s0, s1);
}

// fused GRU
__global__ __launch_bounds__(256) void k_gruf(
    const unsigned short* __restrict__ A, const unsigned short* __restrict__ Wf,
    const float* __restrict__ bih, const float* __restrict__ bhh,
    float* __restrict__ hst, unsigned short* __restrict__ hbf,
    const float* __restrict__ ow, const float* __restrict__ ob,
    float* __restrict__ outp) {
  const int tid = threadIdx.x;
  const int l = tid & 63;
  const int w = tid >> 6;
  const int m0 = blockIdx.x * 64 + w * 16;

  f32x4 acc[24];
#pragma unroll
  for (int nt = 0; nt < 24; nt++) acc[nt] = (f32x4){0.f, 0.f, 0.f, 0.f};
  int arow = m0 + (l & 15);
  if (arow >= BN_) arow = BN_ - 1;
  const unsigned short* Ap = A + (size_t)arow * 128 + ((l >> 4) << 3);
#pragma unroll
  for (int kc = 0; kc < 4; kc++) {
    s8v av = *(const s8v*)(Ap + kc * 32);
#pragma unroll
    for (int nt = 0; nt < 24; nt++) {
      s8v bv = *(const s8v*)(Wf + (((size_t)(kc * 24 + nt)) << 9) + (l << 3));
      acc[nt] = __builtin_amdgcn_mfma_f32_16x16x32_bf16(av, bv, acc[nt], 0, 0, 0);
    }
  }
  const int hi = l >> 4, lo16 = l & 15;
  float p[4] = {0.f, 0.f, 0.f, 0.f};
#pragma unroll
  for (int nt = 0; nt < 8; nt++) {
    int col = nt * 16 + lo16;
    float br = bih[col], bz = bih[col + 128], bn = bih[col + 256];
    float hr = bhh[col], hz = bhh[col + 128], hn = bhh[col + 256];
    float owv = ow[col];
#pragma unroll
    for (int reg = 0; reg < 4; reg++) {
      int row = m0 + hi * 4 + reg;
      if (row >= BN_) continue;
      float r = fast_sigmoid(acc[nt][reg] + br + hr);
      float z = fast_sigmoid(acc[nt + 8][reg] + bz + hz);
      float n = fast_tanh(acc[nt + 16][reg] + bn + r * hn);
      float hv = (1.f - z) * n;  // h0 = 0
      size_t oi = (size_t)row * 128 + col;
      hst[oi] = hv;
      hbf[oi] = f2bf(hv);
      p[reg] = fmaf(hv, owv, p[reg]);
    }
  }
#pragma unroll
  for (int m = 1; m <= 8; m <<= 1)
#pragma unroll
    for (int reg = 0; reg < 4; reg++) p[reg] += __shfl_xor(p[reg], m);
  if (lo16 == 0) {
    float obv = ob[0];
#pragma unroll
    for (int reg = 0; reg < 4; reg++) {
      int row = m0 + hi * 4 + reg;
      if (row < BN_) outp[(size_t)row * FH_ + 0] = p[reg] + obv;
    }
  }
}

extern "C" void kernel_launch(void* const* d_in, const int* in_sizes, int n_in,
                              void* d_out, int out_size, void* d_ws, size_t ws_size,
                              hipStream_t stream) {
  const float* x       = (const float*)d_in[0];
  const float* gcn_w1  = (const float*)d_in[1];
  const float* gcn_b1  = (const float*)d_in[2];
  const float* gcn_w2  = (const float*)d_in[3];
  const float* gcn_b2  = (const float*)d_in[4];
  const float* gcn_w3  = (const float*)d_in[5];
  const float* gcn_b3  = (const float*)d_in[6];
  const float* att_w1  = (const float*)d_in[7];
  const float* att_b1  = (const float*)d_in[8];
  const float* att_w2  = (const float*)d_in[9];
  const float* att_b2  = (const float*)d_in[10];
  const float* gru_wih = (const float*)d_in[11];
  const float* gru_bih = (const float*)d_in[13];
  const float* gru_bhh = (const float*)d_in[14];
  const float* ode_w1  = (const float*)d_in[15];
  const float* ode_b1  = (const float*)d_in[16];
  const float* ode_w2  = (const float*)d_in[17];
  const float* ode_b2  = (const float*)d_in[18];
  const float* out_w   = (const float*)d_in[19];
  const float* out_b   = (const float*)d_in[20];
  const int*   eidx    = (const int*)d_in[21];
  float* out = (float*)d_out;

  float* wsf = (float*)d_ws;
  size_t off = 0;
  unsigned short* h1b12 = (unsigned short*)(wsf + off); off += (size_t)BN_ * 384;
  float* hst    = wsf + off; off += (size_t)BN_ * H_;
  float* scores = wsf + off; off += (size_t)T_ * BN_;
  float* dinv   = wsf + off; off += BN_;
  int2*  ev     = (int2*)(wsf + off); off += (size_t)EVCAP_ * 2;  // 16B-aligned (off%4==0)
  unsigned short* hseqb  = (unsigned short*)(wsf + off); off += (size_t)T_ * BN_ * H_ / 2;
  unsigned short* t1b12  = (unsigned short*)(wsf + off); off += (size_t)T_ * BN_ * H_ / 2;
  unsigned short* hbf    = (unsigned short*)(wsf + off); off += (size_t)BN_ * H_ / 2;
  unsigned short* ubf    = (unsigned short*)(wsf + off); off += (size_t)BN_ * H_ / 2;
  unsigned short* rkb    = (unsigned short*)(wsf + off); off += (size_t)BN_ * H_ / 2;
  unsigned short* nfbf   = (unsigned short*)(wsf + off); off += (size_t)BN_ * H_ / 2;
  unsigned short* w2f    = (unsigned short*)(wsf + off); off += 64 * 128 / 2;
  unsigned short* w3f    = (unsigned short*)(wsf + off); off += 128 * 128 / 2;
  unsigned short* aw1f   = (unsigned short*)(wsf + off); off += 128 * 128 / 2;
  unsigned short* ow1f   = (unsigned short*)(wsf + off); off += 128 * 128 / 2;
  unsigned short* ow2f   = (unsigned short*)(wsf + off); off += 128 * 128 / 2;
  unsigned short* wihf   = (unsigned short*)(wsf + off); off += 128 * 384 / 2;
  int* rp   = (int*)(wsf + off); off += BN_ + 1;
  int* cnt  = (int*)(wsf + off); off += BN_;
  int* ord  = (int*)(wsf + off); off += BN_;
  int* hist = (int*)(wsf + off); off += 256;
  if (ws_size < off * sizeof(float)) {
    k_sentinel<<<1, 1, 0, stream>>>(out);
    return;
  }

  const int* esrc = eidx;
  const int* edst = eidx + E_;
  const int g79 = (BN_ + 255) / 256;

  // ---- CSR build (even-aligned rows, zeroed pads) + degree sort + weight prep ----
  hipMemsetAsync(ev, 0, (size_t)EVCAP_ * sizeof(int2), stream);
  hipMemsetAsync(hist, 0, 256 * sizeof(int), stream);
  k_init_cnt<<<g79, 256, 0, stream>>>(cnt);
  k_count<<<(E_ + 255) / 256, 256, 0, stream>>>(edst, cnt);
  k_scan<<<1, 1024, 0, stream>>>(cnt, rp, dinv);
  k_fill<<<(TOTE_ + 255) / 256, 256, 0, stream>>>(esrc, edst, rp, cnt, ev, dinv);
  k_hist<<<g79, 256, 0, stream>>>(rp, hist);
  k_binscan<<<1, 256, 0, stream>>>(hist);
  k_scatter<<<g79, 256, 0, stream>>>(rp, hist, ord);
  k_prep_all<<<480, 256, 0, stream>>>(gcn_w2, gcn_w3, att_w1, ode_w1, ode_w2, gru_wih,
                                      w2f, w3f, aw1f, ow1f, ow2f, wihf);

  const int gW = BN_ / 4;
  const int gR = (BN_ + 63) / 64;
  const int gF = 1280;

  // ---- spatial encoder: 3 dispatches for all 12 timesteps ----
  k_spl1T<<<gW, 256, 0, stream>>>(rp, ev, x, gcn_w1, gcn_b1, h1b12);
  k_fusedT<64><<<dim3(gF, 12), 256, 0, stream>>>(rp, ev, ord, h1b12, w2f, gcn_b2, t1b12);
  k_fusedT<128><<<dim3(gF, 12), 256, 0, stream>>>(rp, ev, ord, t1b12, w3f, gcn_b3, hseqb);

  // ---- temporal attention ----
  k_att<<<(T_ * BN_ + 63) / 64, 256, 0, stream>>>(hseqb, aw1f, att_b1, T_ * BN_,
                                                  att_w2, att_b2, scores);
  k_attw<<<(BN_ * 64 + 255) / 256, 256, 0, stream>>>(scores, hseqb, nfbf);

  // ---- GRU ----
  k_gruf<<<gR, 256, 0, stream>>>(nfbf, wihf, gru_bih, gru_bhh, hst, hbf,
                                 out_w, out_b, out);

  // ---- graph ODE, RK4: 2 fused dispatches per f-eval ----
  const float dt = (float)FH_ / (float)(FH_ - 1);
  unsigned short* t1 = t1b12;
  auto f_eval = [&](const unsigned short* inbf, int mode, float c1, float c2, int step) {
    k_fused<<<gF, 256, 0, stream>>>(rp, ev, ord, inbf, ow1f, ode_b1, 0, 0.f, 0.f,
                                    t1, nullptr, nullptr, nullptr, nullptr,
                                    nullptr, nullptr, nullptr, 0);
    k_fused<<<gF, 256, 0, stream>>>(rp, ev, ord, t1, ow2f, ode_b2, mode, c1, c2,
                                    nullptr, hbf, rkb, hst,
                                    (mode == 3) ? hbf : ubf,
                                    out_w, out_b, out, step);
  };
  for (int s = 1; s < FH_; s++) {
    f_eval(hbf, 1, 0.5f * dt, 0.f, s);
    f_eval(ubf, 2, 0.5f * dt, 0.f, s);
    f_eval(ubf, 2, dt, 0.f, s);
    f_eval(ubf, 3, 0.f, dt / 6.f, s);
  }
}